// Round 1
// baseline (664.483 us; speedup 1.0000x reference)
//
#include <hip/hip_runtime.h>

// Problem dims
#define NZ 128
#define NY 192
#define NXP 193            // pred_z W
#define NX 192             // d = diff along W -> width 192
#define NVOX (NZ * NY * NX)  // 4718592

// reflect index (jnp.pad mode='reflect': -1 -> 1, n -> n-2)
__device__ __forceinline__ int refl(int i, int n) {
    i = (i < 0) ? -i : i;
    i = (i >= n) ? (2 * n - 2 - i) : i;
    return i;
}

#define MNMX(a, b) { float _mn = fminf(a, b); float _mx = fmaxf(a, b); (a) = _mn; (b) = _mx; }

__global__ void init_ws(double* sum_ws, int* mon_ws) {
    *sum_ws = 0.0;
    *mon_ws = 0;   // bit pattern of 0.0f; monotonicity penalty is >= 0
}

// One thread per d-voxel. Computes:
//  - (d - median3x3x3(d))^2 summed (block partial -> atomicAdd double)
//  - max(1 - d, 0) maxed      (block partial -> atomicMax on float bits)
__global__ __launch_bounds__(256) void loss_main(const float* __restrict__ P,
                                                 double* __restrict__ sum_ws,
                                                 int* __restrict__ mon_ws) {
    int f = blockIdx.x * 256 + threadIdx.x;   // grid covers NVOX exactly
    int x = f % NX;
    int t = f / NX;
    int y = t % NY;
    int z = t / NY;

    // Gather the 27 window d-values with reflect padding.
    float v[27];
#pragma unroll
    for (int dz = 0; dz < 3; ++dz) {
        int zi = refl(z + dz - 1, NZ);
#pragma unroll
        for (int dy = 0; dy < 3; ++dy) {
            int yi = refl(y + dy - 1, NY);
            const float* __restrict__ row = P + ((size_t)zi * NY + yi) * NXP;
#pragma unroll
            for (int dxx = 0; dxx < 3; ++dxx) {
                int xi = refl(x + dxx - 1, NX);
                v[(dz * 3 + dy) * 3 + dxx] = row[xi + 1] - row[xi];
            }
        }
    }

    float dcen = v[13];   // center (dz=dy=dxx=1)

    // ---- exact median of 27 via forgetful selection ----
    // Buffer = v[0..14]. Each iter: min -> v[0], max -> v[14], replace both
    // with two unconsumed values. Dropped min has 14 coexisting elems >= it
    // (rank <= 13 of 27, can't be median); symmetric for max.
#pragma unroll
    for (int it = 0; it < 6; ++it) {
#pragma unroll
        for (int i = 1; i < 15; ++i) MNMX(v[0], v[i]);    // v[0] = min
#pragma unroll
        for (int i = 1; i < 14; ++i) MNMX(v[i], v[14]);   // v[14] = max
        v[0]  = v[15 + 2 * it];
        v[14] = v[16 + 2 * it];
    }
    // Median of the remaining 15 (rank 8) == overall median: peel min&max 6x.
#pragma unroll
    for (int r = 0; r < 6; ++r) {
#pragma unroll
        for (int i = r + 1; i <= 14 - r; ++i) MNMX(v[r], v[i]);
#pragma unroll
        for (int i = r + 1; i < 14 - r; ++i) MNMX(v[i], v[14 - r]);
    }
    float mn  = fminf(v[6], v[7]);
    float mx  = fmaxf(v[6], v[7]);
    float med = fmaxf(mn, fminf(mx, v[8]));

    float diff = dcen - med;
    float s = diff * diff;
    float m = fmaxf(1.0f - dcen, 0.0f);   // -(dz - DZ_MIN)/DX clamped at 0

    // wave64 reduce
#pragma unroll
    for (int off = 32; off > 0; off >>= 1) {
        s += __shfl_down(s, off);
        m = fmaxf(m, __shfl_down(m, off));
    }
    __shared__ float ss[4], sm[4];
    int lane = threadIdx.x & 63, wid = threadIdx.x >> 6;
    if (lane == 0) { ss[wid] = s; sm[wid] = m; }
    __syncthreads();
    if (threadIdx.x == 0) {
        float S = (ss[0] + ss[1]) + (ss[2] + ss[3]);
        float M = fmaxf(fmaxf(sm[0], sm[1]), fmaxf(sm[2], sm[3]));
        atomicAdd(sum_ws, (double)S);
        atomicMax(mon_ws, __float_as_int(M));  // valid: M >= 0, init 0
    }
}

// Exact lower median of z0 = pred_z[...,0] (24576 elems, stride NXP) via
// 4-pass MSB radix select on sign-flipped float bits. Writes out[2] = med^2.
__global__ void median_z0(const float* __restrict__ P, float* __restrict__ out) {
    __shared__ unsigned hist[256];
    __shared__ unsigned s_prefix, s_k;
    const int n = NZ * NY;  // 24576
    int tid = threadIdx.x;
    if (tid == 0) { s_prefix = 0u; s_k = (unsigned)((n - 1) / 2); }  // 12287
    __syncthreads();

    for (int pass = 0; pass < 4; ++pass) {
        for (int i = tid; i < 256; i += (int)blockDim.x) hist[i] = 0u;
        __syncthreads();
        unsigned prefix = s_prefix;
        int shift = 24 - 8 * pass;
        unsigned pmask = (pass == 0) ? 0u : (0xFFFFFFFFu << (shift + 8));
        for (int i = tid; i < n; i += (int)blockDim.x) {
            unsigned bits = __float_as_uint(P[(size_t)i * NXP]);
            unsigned u = bits ^ ((bits & 0x80000000u) ? 0xFFFFFFFFu : 0x80000000u);
            if ((u & pmask) == (prefix & pmask))
                atomicAdd(&hist[(u >> shift) & 0xFFu], 1u);
        }
        __syncthreads();
        if (tid == 0) {
            unsigned k = s_k, cum = 0u, b = 0u;
            for (; b < 255u; ++b) {
                unsigned c = hist[b];
                if (cum + c > k) break;
                cum += c;
            }
            s_prefix = prefix | (b << shift);
            s_k = k - cum;
        }
        __syncthreads();
    }
    if (tid == 0) {
        unsigned u = s_prefix;
        unsigned bits = (u & 0x80000000u) ? (u ^ 0x80000000u) : ~u;
        float med = __uint_as_float(bits);
        out[2] = med * med;
    }
}

__global__ void finalize_k(const double* sum_ws, const int* mon_ws,
                           float* __restrict__ out) {
    out[0] = (float)(*sum_ws * (1.0 / (double)NVOX));
    out[1] = __int_as_float(*mon_ws);
}

extern "C" void kernel_launch(void* const* d_in, const int* in_sizes, int n_in,
                              void* d_out, int out_size, void* d_ws, size_t ws_size,
                              hipStream_t stream) {
    const float* P = (const float*)d_in[0];
    float* out = (float*)d_out;
    double* sum_ws = (double*)d_ws;
    int* mon_ws = (int*)((char*)d_ws + 8);

    hipLaunchKernelGGL(init_ws, dim3(1), dim3(1), 0, stream, sum_ws, mon_ws);
    hipLaunchKernelGGL(loss_main, dim3(NVOX / 256), dim3(256), 0, stream,
                       P, sum_ws, mon_ws);
    hipLaunchKernelGGL(median_z0, dim3(1), dim3(256), 0, stream, P, out);
    hipLaunchKernelGGL(finalize_k, dim3(1), dim3(1), 0, stream,
                       sum_ws, mon_ws, out);
}

// Round 2
// 201.443 us; speedup vs baseline: 3.2986x; 3.2986x over previous
//
#include <hip/hip_runtime.h>

// Problem dims
#define NZ 128
#define NY 192
#define NXP 193            // pred_z W
#define NX 192             // d = diff along W -> width 192
#define NVOX (NZ * NY * NX)
#define NZ0 (NZ * NY)      // 24576 first-column elements

// Output tile per block (x,y,z) and LDS halo tile
#define TX 64
#define TY 8
#define TZ 8
#define LX 66
#define LY 10
#define LZ 10
#define LTOT (LX * LY * LZ)   // 6600 floats = 26.4 KB

// reflect index (jnp.pad mode='reflect': -1 -> 1, n -> n-2)
__device__ __forceinline__ int refl(int i, int n) {
    i = (i < 0) ? -i : i;
    i = (i >= n) ? (2 * n - 2 - i) : i;
    return i;
}

#define MNMX(a, b) { float _mn = fminf(a, b); float _mx = fmaxf(a, b); (a) = _mn; (b) = _mx; }

__device__ __forceinline__ unsigned f2sortable(float f) {
    unsigned bits = __float_as_uint(f);
    return bits ^ ((bits & 0x80000000u) ? 0xFFFFFFFFu : 0x80000000u);
}

// Zero accumulators + (optionally) compact z0 column into sortable uints.
__global__ void gather_init(const float* __restrict__ P, unsigned* __restrict__ u_out,
                            double* sum_ws, int* mon_ws, int do_gather) {
    int i = blockIdx.x * 256 + threadIdx.x;
    if (i == 0) { *sum_ws = 0.0; *mon_ws = 0; }
    if (do_gather && i < NZ0) u_out[i] = f2sortable(P[(size_t)i * NXP]);
}

// LDS-tiled main loss: each block computes a 64x8x8 output tile; each thread
// does 16 outputs (x = tid&63, y-pair = tid>>6, z loop).
__global__ __launch_bounds__(256, 4) void loss_main(const float* __restrict__ P,
                                                    double* __restrict__ sum_ws,
                                                    int* __restrict__ mon_ws) {
    __shared__ float dt[LZ][LY][LX];
    const int tid = threadIdx.x;
    const int x0 = blockIdx.x * TX, y0 = blockIdx.y * TY, z0 = blockIdx.z * TZ;

    // Stage d-tile (with reflect halo) into LDS: 26 iters of 256 threads.
    for (int idx = tid; idx < LTOT; idx += 256) {
        int xx = idx % LX;
        int r  = idx / LX;
        int yy = r % LY;
        int zz = r / LY;
        int gz = refl(z0 + zz - 1, NZ);
        int gy = refl(y0 + yy - 1, NY);
        int gx = refl(x0 + xx - 1, NX);
        const float* __restrict__ row = P + ((size_t)gz * NY + gy) * NXP + gx;
        dt[zz][yy][xx] = row[1] - row[0];
    }
    __syncthreads();

    const int x  = tid & 63;
    const int yg = tid >> 6;
    float s_acc = 0.0f, m_acc = 0.0f;

    for (int z = 0; z < TZ; ++z) {
#pragma unroll
        for (int ys = 0; ys < 2; ++ys) {
            const int y = yg * 2 + ys;
            const float* __restrict__ base = &dt[z][y][x];

            // Batch all 27 window reads (const offsets from one base).
            float v[27];
#pragma unroll
            for (int k = 0; k < 27; ++k) {
                const int dz = k / 9, rr = k % 9, dy = rr / 3, dxx = rr % 3;
                v[k] = base[dz * (LY * LX) + dy * LX + dxx];
            }
            const float dcen = v[13];  // center (1,1,1)

            // Exact median-of-27: forgetful selection (verified round 1).
#pragma unroll
            for (int it = 0; it < 6; ++it) {
#pragma unroll
                for (int i = 1; i < 15; ++i) MNMX(v[0], v[i]);    // min -> v[0]
#pragma unroll
                for (int i = 1; i < 14; ++i) MNMX(v[i], v[14]);   // max -> v[14]
                v[0]  = v[15 + 2 * it];
                v[14] = v[16 + 2 * it];
            }
#pragma unroll
            for (int r = 0; r < 6; ++r) {
#pragma unroll
                for (int i = r + 1; i <= 14 - r; ++i) MNMX(v[r], v[i]);
#pragma unroll
                for (int i = r + 1; i < 14 - r; ++i) MNMX(v[i], v[14 - r]);
            }
            const float mn  = fminf(v[6], v[7]);
            const float mx  = fmaxf(v[6], v[7]);
            const float med = fmaxf(mn, fminf(mx, v[8]));

            const float diff = dcen - med;
            s_acc = fmaf(diff, diff, s_acc);
            m_acc = fmaxf(m_acc, 1.0f - dcen);   // clamp at 0 via init
        }
    }

    // Block reduction: wave shuffle -> LDS -> one atomic pair per block.
#pragma unroll
    for (int off = 32; off > 0; off >>= 1) {
        s_acc += __shfl_down(s_acc, off);
        m_acc = fmaxf(m_acc, __shfl_down(m_acc, off));
    }
    __shared__ float ss[4], sm[4];
    const int lane = tid & 63, wid = tid >> 6;
    if (lane == 0) { ss[wid] = s_acc; sm[wid] = m_acc; }
    __syncthreads();
    if (tid == 0) {
        float S = (ss[0] + ss[1]) + (ss[2] + ss[3]);
        float M = fmaxf(fmaxf(sm[0], sm[1]), fmaxf(sm[2], sm[3]));
        atomicAdd(sum_ws, (double)S);
        atomicMax(mon_ws, __float_as_int(M));  // valid: M >= 0, init 0
    }
}

// Exact lower median of z0 via 4-pass radix select (compact array if
// available, else strided fallback), fused with loss finalization.
__global__ __launch_bounds__(1024) void select_fin(const float* __restrict__ P,
                                                   const unsigned* __restrict__ u_in,
                                                   int have_u,
                                                   const double* __restrict__ sum_ws,
                                                   const int* __restrict__ mon_ws,
                                                   float* __restrict__ out) {
    __shared__ unsigned hist[256];
    __shared__ unsigned s_prefix, s_k;
    const int tid = threadIdx.x;
    if (tid == 0) { s_prefix = 0u; s_k = (unsigned)((NZ0 - 1) / 2); }
    __syncthreads();

    for (int pass = 0; pass < 4; ++pass) {
        if (tid < 256) hist[tid] = 0u;
        __syncthreads();
        const unsigned prefix = s_prefix;
        const int shift = 24 - 8 * pass;
        const unsigned pmask = (pass == 0) ? 0u : (0xFFFFFFFFu << (shift + 8));
        for (int i = tid; i < NZ0; i += 1024) {
            unsigned u = have_u ? u_in[i] : f2sortable(P[(size_t)i * NXP]);
            if ((u & pmask) == (prefix & pmask))
                atomicAdd(&hist[(u >> shift) & 255u], 1u);
        }
        __syncthreads();
        if (tid == 0) {
            unsigned k = s_k, cum = 0u, b = 0u;
            for (; b < 255u; ++b) {
                unsigned c = hist[b];
                if (cum + c > k) break;
                cum += c;
            }
            s_prefix = prefix | (b << shift);
            s_k = k - cum;
        }
        __syncthreads();
    }
    if (tid == 0) {
        const unsigned u = s_prefix;
        const unsigned bits = (u & 0x80000000u) ? (u ^ 0x80000000u) : ~u;
        const float med = __uint_as_float(bits);
        out[2] = med * med;
        out[0] = (float)(*sum_ws / (double)NVOX);
        out[1] = __int_as_float(*mon_ws);
    }
}

extern "C" void kernel_launch(void* const* d_in, const int* in_sizes, int n_in,
                              void* d_out, int out_size, void* d_ws, size_t ws_size,
                              hipStream_t stream) {
    const float* P = (const float*)d_in[0];
    float* out = (float*)d_out;
    double* sum_ws = (double*)d_ws;
    int* mon_ws = (int*)((char*)d_ws + 8);
    unsigned* u_ws = (unsigned*)((char*)d_ws + 16);
    const int have_u = (ws_size >= (size_t)(16 + NZ0 * 4)) ? 1 : 0;

    hipLaunchKernelGGL(gather_init, dim3(NZ0 / 256), dim3(256), 0, stream,
                       P, u_ws, sum_ws, mon_ws, have_u);
    hipLaunchKernelGGL(loss_main, dim3(NX / TX, NY / TY, NZ / TZ), dim3(256), 0, stream,
                       P, sum_ws, mon_ws);
    hipLaunchKernelGGL(select_fin, dim3(1), dim3(1024), 0, stream,
                       P, u_ws, have_u, sum_ws, mon_ws, out);
}

// Round 3
// 126.481 us; speedup vs baseline: 5.2536x; 1.5927x over previous
//
#include <hip/hip_runtime.h>

// Problem dims
#define NZ 128
#define NY 192
#define NXP 193
#define NX 192
#define NVOX (NZ * NY * NX)
#define NZ0 (NZ * NY)      // 24576

// Tile: 32x8 xy outputs per block, 16 z-outputs per thread
#define TX 32
#define TY 8
#define TZ 16
#define LX 34              // TX + 2 halo
#define LY 10              // TY + 2 halo
#define LZ 18              // TZ + 2 halo
#define LSL (LY * LX)      // 340 floats per z-slice
#define LTOT (LZ * LSL)    // 6120 floats = 24480 B

__device__ __forceinline__ int refl(int i, int n) {
    i = (i < 0) ? -i : i;
    i = (i >= n) ? (2 * n - 2 - i) : i;
    return i;
}

__device__ __forceinline__ unsigned f2sortable(float f) {
    unsigned bits = __float_as_uint(f);
    return bits ^ ((bits & 0x80000000u) ? 0xFFFFFFFFu : 0x80000000u);
}

// ---- Batcher odd-even merge (valid for any sorted inputs, any M,N) ----
template<int M, int N>
struct OEM {
    static __device__ __forceinline__ void run(const float* a, const float* b, float* out) {
        if constexpr (M == 0) {
#pragma unroll
            for (int i = 0; i < N; ++i) out[i] = b[i];
        } else if constexpr (N == 0) {
#pragma unroll
            for (int i = 0; i < M; ++i) out[i] = a[i];
        } else if constexpr (M == 1 && N == 1) {
            out[0] = fminf(a[0], b[0]);
            out[1] = fmaxf(a[0], b[0]);
        } else {
            constexpr int ME = (M + 1) / 2, MO = M / 2, NE = (N + 1) / 2, NO = N / 2;
            float ae[ME], be[NE];
            float ao[MO > 0 ? MO : 1], bo[NO > 0 ? NO : 1];
#pragma unroll
            for (int i = 0; i < ME; ++i) ae[i] = a[2 * i];
#pragma unroll
            for (int i = 0; i < MO; ++i) ao[i] = a[2 * i + 1];
#pragma unroll
            for (int i = 0; i < NE; ++i) be[i] = b[2 * i];
#pragma unroll
            for (int i = 0; i < NO; ++i) bo[i] = b[2 * i + 1];
            constexpr int EL = ME + NE, OL = MO + NO;
            float e[EL];
            float o[OL > 0 ? OL : 1];
            OEM<ME, NE>::run(ae, be, e);
            OEM<MO, NO>::run(ao, bo, o);
            constexpr int P = (OL < EL - 1) ? OL : (EL - 1);
            out[0] = e[0];
#pragma unroll
            for (int i = 0; i < P; ++i) {
                out[2 * i + 1] = fminf(o[i], e[i + 1]);
                out[2 * i + 2] = fmaxf(o[i], e[i + 1]);
            }
            if constexpr (EL == OL)           out[M + N - 1] = o[OL - 1];
            else if constexpr (EL == OL + 2)  out[M + N - 1] = e[EL - 1];
        }
    }
};

template<int N>
struct OES {
    static __device__ __forceinline__ void run(const float* in, float* out) {
        if constexpr (N == 1) {
            out[0] = in[0];
        } else {
            constexpr int H = N / 2;
            float s1[H], s2[N - H];
            OES<H>::run(in, s1);
            OES<N - H>::run(in + H, s2);
            OEM<H, N - H>::run(s1, s2, out);
        }
    }
};

// Zero accumulators + compact z0 column into sortable uints (for radix select).
__global__ void gather_init(const float* __restrict__ P, unsigned* __restrict__ u_out,
                            double* sum_ws, int* mon_ws, int do_gather) {
    int i = blockIdx.x * 256 + threadIdx.x;
    if (i == 0) { *sum_ws = 0.0; *mon_ws = 0; }
    if (do_gather && i < NZ0) u_out[i] = f2sortable(P[(size_t)i * NXP]);
}

// Main loss: per-thread sliding z-window with sorted-slice reuse.
// med27 = min over i of max(A[i-1], S_{14-i}), S = merge of the other 2 slices.
__global__ __launch_bounds__(256, 4) void loss_main(const float* __restrict__ P,
                                                    double* __restrict__ sum_ws,
                                                    int* __restrict__ mon_ws) {
    __shared__ float dt[LTOT];
    const int tid = threadIdx.x;
    const int x0 = blockIdx.x * TX, y0 = blockIdx.y * TY, z0t = blockIdx.z * TZ;

    // Stage d-tile (reflect halo) into LDS.
    for (int idx = tid; idx < LTOT; idx += 256) {
        int xx = idx % LX;
        int r  = idx / LX;
        int yy = r % LY;
        int zz = r / LY;
        int gz = refl(z0t + zz - 1, NZ);
        int gy = refl(y0 + yy - 1, NY);
        int gx = refl(x0 + xx - 1, NX);
        const float* __restrict__ row = P + ((size_t)gz * NY + gy) * NXP + gx;
        dt[idx] = row[1] - row[0];
    }
    __syncthreads();

    const int x = tid & 31;       // 0..31
    const int y = tid >> 5;       // 0..7
    const int cbase = y * LX + x; // window rows y..y+2, cols x..x+2 (halo offset)

    float t9[9], S0[9], S1[9], S2[9], M18[18];

    // read 3x3 of slice sl at this (x,y)
    auto rd9 = [&](int sl, float* v) {
        const float* __restrict__ b = &dt[sl * LSL + cbase];
#pragma unroll
        for (int dy = 0; dy < 3; ++dy)
#pragma unroll
            for (int dxx = 0; dxx < 3; ++dxx)
                v[dy * 3 + dxx] = b[dy * LX + dxx];
    };

    rd9(0, t9); OES<9>::run(t9, S0);
    rd9(1, t9); OES<9>::run(t9, S1);
    float cent = t9[4];           // center of slice 1 = dcen for t=0
    float s_acc = 0.0f, m_acc = 0.0f;

#pragma unroll
    for (int t = 0; t < TZ; ++t) {
        rd9(t + 2, t9);
        float cnext = t9[4];
        OES<9>::run(t9, S2);

        float med;
        if ((t & 1) == 0) {
            // window slices (t, t+1, t+2): A = S0, merge (S1,S2)
            OEM<9, 9>::run(S1, S2, M18);
            med = M18[13];
#pragma unroll
            for (int i = 0; i < 9; ++i) med = fminf(med, fmaxf(S0[i], M18[12 - i]));
        } else {
            // M18 still = merge(slice t, t+1); A = S2 (slice t+2)
            med = M18[13];
#pragma unroll
            for (int i = 0; i < 9; ++i) med = fminf(med, fmaxf(S2[i], M18[12 - i]));
        }

        float diff = cent - med;
        s_acc = fmaf(diff, diff, s_acc);
        m_acc = fmaxf(m_acc, 1.0f - cent);
        cent = cnext;
#pragma unroll
        for (int i = 0; i < 9; ++i) { S0[i] = S1[i]; S1[i] = S2[i]; }
    }

    // Block reduction -> one atomic pair.
#pragma unroll
    for (int off = 32; off > 0; off >>= 1) {
        s_acc += __shfl_down(s_acc, off);
        m_acc = fmaxf(m_acc, __shfl_down(m_acc, off));
    }
    __shared__ float ss[4], sm[4];
    const int lane = tid & 63, wid = tid >> 6;
    if (lane == 0) { ss[wid] = s_acc; sm[wid] = m_acc; }
    __syncthreads();
    if (tid == 0) {
        float S = (ss[0] + ss[1]) + (ss[2] + ss[3]);
        float M = fmaxf(fmaxf(sm[0], sm[1]), fmaxf(sm[2], sm[3]));
        atomicAdd(sum_ws, (double)S);
        atomicMax(mon_ws, __float_as_int(M));
    }
}

// Exact lower median of z0 via 3-pass (11/11/10 bit) radix select + finalize.
__global__ __launch_bounds__(1024) void select_fin(const float* __restrict__ P,
                                                   const unsigned* __restrict__ u_in,
                                                   int have_u,
                                                   const double* __restrict__ sum_ws,
                                                   const int* __restrict__ mon_ws,
                                                   float* __restrict__ out) {
    __shared__ unsigned hist[2048];
    __shared__ unsigned wsum[16], woff[16];
    __shared__ unsigned s_pref, s_k, s_bucket, s_rem;
    const int tid = threadIdx.x;
    const int lane = tid & 63, wid = tid >> 6;

    if (tid == 0) { s_pref = 0u; s_k = (unsigned)((NZ0 - 1) / 2); }
    __syncthreads();

    const int sh[3]    = {21, 10, 0};
    const int nbits[3] = {11, 11, 10};

    for (int p = 0; p < 3; ++p) {
        hist[tid] = 0u; hist[tid + 1024] = 0u;
        __syncthreads();
        const unsigned pref = s_pref;
        const unsigned kk = s_k;
        const int nb = 1 << nbits[p];
        const unsigned bmask = (unsigned)(nb - 1);

        for (int i = tid; i < NZ0; i += 1024) {
            unsigned u = have_u ? u_in[i] : f2sortable(P[(size_t)i * NXP]);
            bool ok = (p == 0) || ((u >> sh[p - 1]) == pref);
            if (ok) atomicAdd(&hist[(u >> sh[p]) & bmask], 1u);
        }
        __syncthreads();

        // parallel exclusive prefix over nb bins (bpt bins per thread)
        const int bpt = nb >> 10;   // 2,2,1
        unsigned mysum = 0u;
#pragma unroll 2
        for (int j = 0; j < bpt; ++j) mysum += hist[tid * bpt + j];
        unsigned inc = mysum;
#pragma unroll
        for (int d = 1; d < 64; d <<= 1) {
            unsigned xx = __shfl_up(inc, d);
            if (lane >= d) inc += xx;
        }
        if (lane == 63) wsum[wid] = inc;
        __syncthreads();
        if (tid == 0) {
            unsigned acc = 0u;
            for (int w = 0; w < 16; ++w) { woff[w] = acc; acc += wsum[w]; }
        }
        __syncthreads();
        unsigned exc = woff[wid] + (inc - mysum);
#pragma unroll 2
        for (int j = 0; j < bpt; ++j) {
            unsigned c = hist[tid * bpt + j];
            if (exc <= kk && kk < exc + c) { s_bucket = (unsigned)(tid * bpt + j); s_rem = kk - exc; }
            exc += c;
        }
        __syncthreads();
        if (tid == 0) { s_pref = (s_pref << nbits[p]) | s_bucket; s_k = s_rem; }
        __syncthreads();
    }

    if (tid == 0) {
        const unsigned u = s_pref;   // full 32-bit sortable value of the median
        const unsigned bits = (u & 0x80000000u) ? (u ^ 0x80000000u) : ~u;
        const float med = __uint_as_float(bits);
        out[2] = med * med;
        out[0] = (float)(*sum_ws / (double)NVOX);
        out[1] = __int_as_float(*mon_ws);
    }
}

extern "C" void kernel_launch(void* const* d_in, const int* in_sizes, int n_in,
                              void* d_out, int out_size, void* d_ws, size_t ws_size,
                              hipStream_t stream) {
    const float* P = (const float*)d_in[0];
    float* out = (float*)d_out;
    double* sum_ws = (double*)d_ws;
    int* mon_ws = (int*)((char*)d_ws + 8);
    unsigned* u_ws = (unsigned*)((char*)d_ws + 16);
    const int have_u = (ws_size >= (size_t)(16 + NZ0 * 4)) ? 1 : 0;

    hipLaunchKernelGGL(gather_init, dim3(NZ0 / 256), dim3(256), 0, stream,
                       P, u_ws, sum_ws, mon_ws, have_u);
    hipLaunchKernelGGL(loss_main, dim3(NX / TX, NY / TY, NZ / TZ), dim3(256), 0, stream,
                       P, sum_ws, mon_ws);
    hipLaunchKernelGGL(select_fin, dim3(1), dim3(1024), 0, stream,
                       P, u_ws, have_u, sum_ws, mon_ws, out);
}

// Round 4
// 113.041 us; speedup vs baseline: 5.8783x; 1.1189x over previous
//
#include <hip/hip_runtime.h>

// Problem dims
#define NZ 128
#define NY 192
#define NXP 193
#define NX 192
#define NVOX (NZ * NY * NX)
#define NZ0 (NZ * NY)      // 24576

// Tile: 32 x 16 xy outputs per block (2 chains/thread at y, y+8), 8 z-outputs
#define TX 32
#define TY 16
#define TZ 8
#define LX 34              // TX + 2
#define LY 18              // TY + 2
#define LZ 10              // TZ + 2
#define LSL (LY * LX)      // 612 floats per z-slice
#define LTOT (LZ * LSL)    // 6120 floats = 24480 B

#define GX (NX / TX)       // 6
#define GY (NY / TY)       // 12
#define GZ (NZ / TZ)       // 16
#define NBLK (GX * GY * GZ) // 1152

// Device-global scratch (persistent, zero-init at load; re-written every call)
__device__ double   g_ps[NBLK];
__device__ float    g_pm[NBLK];
__device__ unsigned g_hist[2048];
__device__ unsigned g_u[NZ0];
__device__ unsigned g_ticket;
__device__ unsigned g_b1, g_k1;

__device__ __forceinline__ int refl(int i, int n) {
    i = (i < 0) ? -i : i;
    i = (i >= n) ? (2 * n - 2 - i) : i;
    return i;
}

__device__ __forceinline__ unsigned f2sortable(float f) {
    unsigned bits = __float_as_uint(f);
    return bits ^ ((bits & 0x80000000u) ? 0xFFFFFFFFu : 0x80000000u);
}

// ---- Batcher odd-even merge / sort (verified rounds 2-3, absmax 0) ----
template<int M, int N>
struct OEM {
    static __device__ __forceinline__ void run(const float* a, const float* b, float* out) {
        if constexpr (M == 0) {
#pragma unroll
            for (int i = 0; i < N; ++i) out[i] = b[i];
        } else if constexpr (N == 0) {
#pragma unroll
            for (int i = 0; i < M; ++i) out[i] = a[i];
        } else if constexpr (M == 1 && N == 1) {
            out[0] = fminf(a[0], b[0]);
            out[1] = fmaxf(a[0], b[0]);
        } else {
            constexpr int ME = (M + 1) / 2, MO = M / 2, NE = (N + 1) / 2, NO = N / 2;
            float ae[ME], be[NE];
            float ao[MO > 0 ? MO : 1], bo[NO > 0 ? NO : 1];
#pragma unroll
            for (int i = 0; i < ME; ++i) ae[i] = a[2 * i];
#pragma unroll
            for (int i = 0; i < MO; ++i) ao[i] = a[2 * i + 1];
#pragma unroll
            for (int i = 0; i < NE; ++i) be[i] = b[2 * i];
#pragma unroll
            for (int i = 0; i < NO; ++i) bo[i] = b[2 * i + 1];
            constexpr int EL = ME + NE, OL = MO + NO;
            float e[EL];
            float o[OL > 0 ? OL : 1];
            OEM<ME, NE>::run(ae, be, e);
            OEM<MO, NO>::run(ao, bo, o);
            constexpr int P = (OL < EL - 1) ? OL : (EL - 1);
            out[0] = e[0];
#pragma unroll
            for (int i = 0; i < P; ++i) {
                out[2 * i + 1] = fminf(o[i], e[i + 1]);
                out[2 * i + 2] = fmaxf(o[i], e[i + 1]);
            }
            if constexpr (EL == OL)           out[M + N - 1] = o[OL - 1];
            else if constexpr (EL == OL + 2)  out[M + N - 1] = e[EL - 1];
        }
    }
};

template<int N>
struct OES {
    static __device__ __forceinline__ void run(const float* in, float* out) {
        if constexpr (N == 1) {
            out[0] = in[0];
        } else {
            constexpr int H = N / 2;
            float s1[H], s2[N - H];
            OES<H>::run(in, s1);
            OES<N - H>::run(in + H, s2);
            OEM<H, N - H>::run(s1, s2, out);
        }
    }
};

// med27 = min( M[13], min_i max(A[i], M[12-i]) ), tree-shaped (depth ~5)
__device__ __forceinline__ float sel27(const float* A, const float* M) {
    float t0 = fmaxf(A[0], M[12]);
    float t1 = fmaxf(A[1], M[11]);
    float t2 = fmaxf(A[2], M[10]);
    float t3 = fmaxf(A[3], M[9]);
    float t4 = fmaxf(A[4], M[8]);
    float t5 = fmaxf(A[5], M[7]);
    float t6 = fmaxf(A[6], M[6]);
    float t7 = fmaxf(A[7], M[5]);
    float t8 = fmaxf(A[8], M[4]);
    float r0 = fminf(fminf(t0, t1), fminf(t2, t3));
    float r1 = fminf(fminf(t4, t5), fminf(t6, t7));
    return fminf(fminf(r0, r1), fminf(t8, M[13]));
}

__global__ __launch_bounds__(256, 3) void loss_main(const float* __restrict__ P) {
    __shared__ float dt[LTOT];
    const int tid = threadIdx.x;
    const int x0 = blockIdx.x * TX, y0 = blockIdx.y * TY, z0t = blockIdx.z * TZ;
    const int bf = blockIdx.x + GX * (blockIdx.y + GY * blockIdx.z);

    // Block 0 re-zeroes the radix-select scratch for zhist (stream-ordered).
    if (bf == 0) {
        for (int j = tid; j < 2048; j += 256) g_hist[j] = 0u;
        if (tid == 0) g_ticket = 0u;
    }

    // ---- Stage d-tile (reflect halo) into LDS; div/mod hoisted out of zz loop
    int goff[3], lp[3];
#pragma unroll
    for (int k = 0; k < 3; ++k) {
        int p = tid + 256 * k;
        lp[k] = (p < LSL) ? p : -1;
        if (p < LSL) {
            int xx = p % LX, yy = p / LX;
            int gy = refl(y0 + yy - 1, NY);
            int gx = refl(x0 + xx - 1, NX);
            goff[k] = gy * NXP + gx;
        }
    }
    for (int zz = 0; zz < LZ; ++zz) {
        int gz = refl(z0t + zz - 1, NZ);
        const float* __restrict__ pl = P + (size_t)gz * (NY * NXP);
#pragma unroll
        for (int k = 0; k < 3; ++k) {
            if (lp[k] >= 0) {
                float a = pl[goff[k]];
                float b = pl[goff[k] + 1];
                dt[zz * LSL + lp[k]] = b - a;
            }
        }
    }
    __syncthreads();

    const int x = tid & 31;
    const int y = tid >> 5;             // 0..7; chains at y and y+8
    const int lbA = y * LX + x;
    const int lbB = lbA + 8 * LX;

    auto rd9 = [&](int base, float* v) {
#pragma unroll
        for (int dy = 0; dy < 3; ++dy)
#pragma unroll
            for (int dxx = 0; dxx < 3; ++dxx)
                v[dy * 3 + dxx] = dt[base + dy * LX + dxx];
    };

    float SA0[9], SA1[9], SA2[9], SB0[9], SB1[9], SB2[9];
    float cA, cB, s_acc = 0.0f, m_acc = 0.0f;

    {
        float a9[9], b9[9];
        rd9(lbA, a9);            rd9(lbB, b9);
        OES<9>::run(a9, SA0);    OES<9>::run(b9, SB0);
        rd9(lbA + LSL, a9);      rd9(lbB + LSL, b9);
        cA = a9[4];              cB = b9[4];
        OES<9>::run(a9, SA1);    OES<9>::run(b9, SB1);
    }

    // One pair = 2 z-steps; roles rotate (X=oldest, Y=mid, Z=new-even slot).
    auto pairstep = [&](float (&XA)[9], float (&YA)[9], float (&ZA)[9],
                        float (&XB)[9], float (&YB)[9], float (&ZB)[9], int t) {
        float a9[9], b9[9], MA[18], MB[18];
        // even step t: window (t, t+1, t+2)
        rd9(lbA + (t + 2) * LSL, a9);
        rd9(lbB + (t + 2) * LSL, b9);
        float cnA = a9[4], cnB = b9[4];
        OES<9>::run(a9, ZA);            OES<9>::run(b9, ZB);
        OEM<9, 9>::run(YA, ZA, MA);     OEM<9, 9>::run(YB, ZB, MB);
        float medA = sel27(XA, MA), medB = sel27(XB, MB);
        float dA = cA - medA, dB = cB - medB;
        s_acc = fmaf(dA, dA, fmaf(dB, dB, s_acc));
        m_acc = fmaxf(m_acc, fmaxf(1.0f - cA, 1.0f - cB));
        cA = cnA; cB = cnB;
        // odd step t+1: window (t+1, t+2, t+3); M reused, new slice -> X
        rd9(lbA + (t + 3) * LSL, a9);
        rd9(lbB + (t + 3) * LSL, b9);
        cnA = a9[4]; cnB = b9[4];
        OES<9>::run(a9, XA);            OES<9>::run(b9, XB);
        medA = sel27(XA, MA);           medB = sel27(XB, MB);
        dA = cA - medA; dB = cB - medB;
        s_acc = fmaf(dA, dA, fmaf(dB, dB, s_acc));
        m_acc = fmaxf(m_acc, fmaxf(1.0f - cA, 1.0f - cB));
        cA = cnA; cB = cnB;
    };

    // Rotation: after a pair, oldest=Z, mid=X, spare=Y  =>  (X,Y,Z)->(Z,X,Y)
    pairstep(SA0, SA1, SA2, SB0, SB1, SB2, 0);
    pairstep(SA2, SA0, SA1, SB2, SB0, SB1, 2);
    pairstep(SA1, SA2, SA0, SB1, SB2, SB0, 4);
    pairstep(SA0, SA1, SA2, SB0, SB1, SB2, 6);

    // Block reduction -> per-block partial (plain stores, no atomics/init).
#pragma unroll
    for (int off = 32; off > 0; off >>= 1) {
        s_acc += __shfl_down(s_acc, off);
        m_acc = fmaxf(m_acc, __shfl_down(m_acc, off));
    }
    __shared__ float ss[4], sm[4];
    const int lane = tid & 63, wid = tid >> 6;
    if (lane == 0) { ss[wid] = s_acc; sm[wid] = m_acc; }
    __syncthreads();
    if (tid == 0) {
        float S = (ss[0] + ss[1]) + (ss[2] + ss[3]);
        float M = fmaxf(fmaxf(sm[0], sm[1]), fmaxf(sm[2], sm[3]));
        g_ps[bf] = (double)S;
        g_pm[bf] = M;
    }
}

// Compact z0 -> sortable uints + global top-11-bit histogram; ticket-elected
// last block picks the median bucket (b1) and in-bucket rank (k1).
__global__ __launch_bounds__(256) void zhist(const float* __restrict__ P) {
    __shared__ unsigned h[2048];
    __shared__ unsigned s_last, wsum[4], woff[4];
    const int tid = threadIdx.x;
    for (int j = tid; j < 2048; j += 256) h[j] = 0u;
    __syncthreads();
    const int i = blockIdx.x * 256 + tid;
    unsigned u = f2sortable(P[(size_t)i * NXP]);
    g_u[i] = u;
    atomicAdd(&h[u >> 21], 1u);
    __syncthreads();
    for (int j = tid; j < 2048; j += 256) {
        unsigned c = h[j];
        if (c) atomicAdd(&g_hist[j], c);
    }
    __threadfence();
    if (tid == 0) s_last = atomicAdd(&g_ticket, 1u);
    __syncthreads();
    if (s_last != (unsigned)(gridDim.x - 1)) return;

    // Last block: parallel scan over 2048 bins, find bucket containing k.
    unsigned my[8], mysum = 0u;
#pragma unroll
    for (int j = 0; j < 8; ++j) { my[j] = atomicAdd(&g_hist[tid * 8 + j], 0u); mysum += my[j]; }
    unsigned inc = mysum;
    const int lane = tid & 63, wid = tid >> 6;
#pragma unroll
    for (int d = 1; d < 64; d <<= 1) {
        unsigned t2 = __shfl_up(inc, d);
        if (lane >= d) inc += t2;
    }
    if (lane == 63) wsum[wid] = inc;
    __syncthreads();
    if (tid == 0) { unsigned a = 0; for (int w = 0; w < 4; ++w) { woff[w] = a; a += wsum[w]; } }
    __syncthreads();
    unsigned exc = woff[wid] + inc - mysum;
    const unsigned kk = (NZ0 - 1) / 2;   // 12287
#pragma unroll
    for (int j = 0; j < 8; ++j) {
        unsigned c = my[j];
        if (exc <= kk && kk < exc + c) { g_b1 = (unsigned)(tid * 8 + j); g_k1 = kk - exc; }
        exc += c;
    }
}

// Candidate counting-select (typical bucket ~10 elems) + partial reduction.
__global__ __launch_bounds__(1024) void final_k(float* __restrict__ out) {
    __shared__ unsigned cand[2048];      // candidates, or radix hist (fallback)
    __shared__ unsigned s_cnt, s_med, s_b, s_r;
    __shared__ unsigned wsum[16], woff[16];
    const int tid = threadIdx.x;
    const int lane = tid & 63, wid = tid >> 6;
    const unsigned b1 = g_b1, k1 = g_k1;

    if (tid == 0) s_cnt = 0u;
    __syncthreads();
    for (int i = tid; i < NZ0; i += 1024) {
        unsigned u = g_u[i];
        if ((u >> 21) == b1) {
            unsigned idx = atomicAdd(&s_cnt, 1u);
            if (idx < 2048u) cand[idx] = u;
        }
    }
    __syncthreads();
    const unsigned m = s_cnt;

    if (m <= 2048u) {
        // exact k1-th smallest among m candidates by counting
        for (int i = tid; i < (int)m; i += 1024) {
            unsigned c = cand[i], less = 0u, eq = 0u;
            for (unsigned j = 0; j < m; ++j) {
                unsigned v = cand[j];
                less += (v < c); eq += (v == c);
            }
            if (less <= k1 && k1 < less + eq) s_med = c;
        }
        __syncthreads();
    } else {
        // fallback: 11-bit + 10-bit radix passes over g_u (filtered)
        unsigned pref = b1, kk = k1;
        for (int j = tid; j < 2048; j += 1024) cand[j] = 0u;
        __syncthreads();
        for (int i = tid; i < NZ0; i += 1024) {
            unsigned u = g_u[i];
            if ((u >> 21) == pref) atomicAdd(&cand[(u >> 10) & 2047u], 1u);
        }
        __syncthreads();
        {
            unsigned c0 = cand[tid * 2], c1 = cand[tid * 2 + 1];
            unsigned mysum = c0 + c1, inc = mysum;
#pragma unroll
            for (int d = 1; d < 64; d <<= 1) { unsigned t2 = __shfl_up(inc, d); if (lane >= d) inc += t2; }
            if (lane == 63) wsum[wid] = inc;
            __syncthreads();
            if (tid == 0) { unsigned a = 0; for (int w = 0; w < 16; ++w) { woff[w] = a; a += wsum[w]; } }
            __syncthreads();
            unsigned exc = woff[wid] + inc - mysum;
            if (exc <= kk && kk < exc + c0) { s_b = tid * 2u; s_r = kk - exc; }
            exc += c0;
            if (exc <= kk && kk < exc + c1) { s_b = tid * 2u + 1u; s_r = kk - exc; }
        }
        __syncthreads();
        pref = (pref << 11) | s_b; kk = s_r;
        __syncthreads();
        for (int j = tid; j < 1024; j += 1024) cand[j] = 0u;
        __syncthreads();
        for (int i = tid; i < NZ0; i += 1024) {
            unsigned u = g_u[i];
            if ((u >> 10) == pref) atomicAdd(&cand[u & 1023u], 1u);
        }
        __syncthreads();
        {
            unsigned c0 = cand[tid], mysum = c0, inc = mysum;
#pragma unroll
            for (int d = 1; d < 64; d <<= 1) { unsigned t2 = __shfl_up(inc, d); if (lane >= d) inc += t2; }
            if (lane == 63) wsum[wid] = inc;
            __syncthreads();
            if (tid == 0) { unsigned a = 0; for (int w = 0; w < 16; ++w) { woff[w] = a; a += wsum[w]; } }
            __syncthreads();
            unsigned exc = woff[wid] + inc - mysum;
            if (exc <= kk && kk < exc + c0) s_b = (unsigned)tid;
        }
        __syncthreads();
        if (tid == 0) s_med = (pref << 10) | s_b;
        __syncthreads();
    }

    // Reduce the 1152 per-block partials (deterministic fixed tree).
    double s = 0.0; float mm = 0.0f;
    if (tid < NBLK) { s = g_ps[tid]; mm = g_pm[tid]; }
    if (tid < NBLK - 1024) { s += g_ps[1024 + tid]; mm = fmaxf(mm, g_pm[1024 + tid]); }
#pragma unroll
    for (int off = 32; off > 0; off >>= 1) {
        s += __shfl_down(s, off);
        mm = fmaxf(mm, __shfl_down(mm, off));
    }
    __shared__ double sd[16];
    __shared__ float sf[16];
    if (lane == 0) { sd[wid] = s; sf[wid] = mm; }
    __syncthreads();
    if (tid == 0) {
        double S = 0.0; float M = 0.0f;
        for (int w = 0; w < 16; ++w) { S += sd[w]; M = fmaxf(M, sf[w]); }
        unsigned u = s_med;
        unsigned bits = (u & 0x80000000u) ? (u ^ 0x80000000u) : ~u;
        float med = __uint_as_float(bits);
        out[0] = (float)(S / (double)NVOX);
        out[1] = M;
        out[2] = med * med;
    }
}

extern "C" void kernel_launch(void* const* d_in, const int* in_sizes, int n_in,
                              void* d_out, int out_size, void* d_ws, size_t ws_size,
                              hipStream_t stream) {
    const float* P = (const float*)d_in[0];
    float* out = (float*)d_out;

    hipLaunchKernelGGL(loss_main, dim3(GX, GY, GZ), dim3(256), 0, stream, P);
    hipLaunchKernelGGL(zhist, dim3(NZ0 / 256), dim3(256), 0, stream, P);
    hipLaunchKernelGGL(final_k, dim3(1), dim3(1024), 0, stream, out);
}

// Round 5
// 104.539 us; speedup vs baseline: 6.3563x; 1.0813x over previous
//
#include <hip/hip_runtime.h>

// Problem dims
#define NZ 128
#define NY 192
#define NXP 193
#define NX 192
#define NVOX (NZ * NY * NX)
#define NZ0 (NZ * NY)      // 24576

// Tile: 32 x 16 xy outputs per block (2 chains/thread at y, y+8), 8 z-outputs
#define TX 32
#define TY 16
#define TZ 8
#define LX 34              // TX + 2
#define LY 18              // TY + 2
#define LZ 10              // TZ + 2
#define LSL (LY * LX)      // 612 floats per z-slice
#define LTOT (LZ * LSL)    // 6120 floats = 24480 B

#define GX (NX / TX)       // 6
#define GY (NY / TY)       // 12
#define GZ (NZ / TZ)       // 16
#define NBLK (GX * GY * GZ) // 1152
#define ZB (NZ0 / 256)     // 96 z0-gather blocks (dispatched first)

// Device-global scratch. Lifecycle: g_hist is zero at entry to every call
// (zero-init at load; re-zeroed at the end of final_k), g_ps/g_pm/g_u are
// fully overwritten every call before being read.
__device__ double   g_ps[NBLK];
__device__ float    g_pm[NBLK];
__device__ unsigned g_hist[2048];
__device__ unsigned g_u[NZ0];

__device__ __forceinline__ int refl(int i, int n) {
    i = (i < 0) ? -i : i;
    i = (i >= n) ? (2 * n - 2 - i) : i;
    return i;
}

__device__ __forceinline__ unsigned f2sortable(float f) {
    unsigned bits = __float_as_uint(f);
    return bits ^ ((bits & 0x80000000u) ? 0xFFFFFFFFu : 0x80000000u);
}

// ---- Batcher odd-even merge / sort (verified rounds 2-4, absmax 0) ----
template<int M, int N>
struct OEM {
    static __device__ __forceinline__ void run(const float* a, const float* b, float* out) {
        if constexpr (M == 0) {
#pragma unroll
            for (int i = 0; i < N; ++i) out[i] = b[i];
        } else if constexpr (N == 0) {
#pragma unroll
            for (int i = 0; i < M; ++i) out[i] = a[i];
        } else if constexpr (M == 1 && N == 1) {
            out[0] = fminf(a[0], b[0]);
            out[1] = fmaxf(a[0], b[0]);
        } else {
            constexpr int ME = (M + 1) / 2, MO = M / 2, NE = (N + 1) / 2, NO = N / 2;
            float ae[ME], be[NE];
            float ao[MO > 0 ? MO : 1], bo[NO > 0 ? NO : 1];
#pragma unroll
            for (int i = 0; i < ME; ++i) ae[i] = a[2 * i];
#pragma unroll
            for (int i = 0; i < MO; ++i) ao[i] = a[2 * i + 1];
#pragma unroll
            for (int i = 0; i < NE; ++i) be[i] = b[2 * i];
#pragma unroll
            for (int i = 0; i < NO; ++i) bo[i] = b[2 * i + 1];
            constexpr int EL = ME + NE, OL = MO + NO;
            float e[EL];
            float o[OL > 0 ? OL : 1];
            OEM<ME, NE>::run(ae, be, e);
            OEM<MO, NO>::run(ao, bo, o);
            constexpr int P = (OL < EL - 1) ? OL : (EL - 1);
            out[0] = e[0];
#pragma unroll
            for (int i = 0; i < P; ++i) {
                out[2 * i + 1] = fminf(o[i], e[i + 1]);
                out[2 * i + 2] = fmaxf(o[i], e[i + 1]);
            }
            if constexpr (EL == OL)           out[M + N - 1] = o[OL - 1];
            else if constexpr (EL == OL + 2)  out[M + N - 1] = e[EL - 1];
        }
    }
};

template<int N>
struct OES {
    static __device__ __forceinline__ void run(const float* in, float* out) {
        if constexpr (N == 1) {
            out[0] = in[0];
        } else {
            constexpr int H = N / 2;
            float s1[H], s2[N - H];
            OES<H>::run(in, s1);
            OES<N - H>::run(in + H, s2);
            OEM<H, N - H>::run(s1, s2, out);
        }
    }
};

// med27 = min( M[13], min_i max(A[i], M[12-i]) ), tree-shaped (depth ~5)
__device__ __forceinline__ float sel27(const float* A, const float* M) {
    float t0 = fmaxf(A[0], M[12]);
    float t1 = fmaxf(A[1], M[11]);
    float t2 = fmaxf(A[2], M[10]);
    float t3 = fmaxf(A[3], M[9]);
    float t4 = fmaxf(A[4], M[8]);
    float t5 = fmaxf(A[5], M[7]);
    float t6 = fmaxf(A[6], M[6]);
    float t7 = fmaxf(A[7], M[5]);
    float t8 = fmaxf(A[8], M[4]);
    float r0 = fminf(fminf(t0, t1), fminf(t2, t3));
    float r1 = fminf(fminf(t4, t5), fminf(t6, t7));
    return fminf(fminf(r0, r1), fminf(t8, M[13]));
}

// Fused: blocks 0..ZB-1 gather z0 + build global histogram (overlaps with
// the loss tiles, which are blocks ZB..ZB+NBLK-1).
__global__ __launch_bounds__(256, 3) void fused_main(const float* __restrict__ P) {
    __shared__ float dt[LTOT];
    const int tid = threadIdx.x;
    const int bid = blockIdx.x;

    if (bid < ZB) {
        // ---- z0 gather + histogram role ----
        unsigned* h = (unsigned*)dt;
        for (int j = tid; j < 2048; j += 256) h[j] = 0u;
        __syncthreads();
        const int i = bid * 256 + tid;
        unsigned u = f2sortable(P[(size_t)i * NXP]);
        g_u[i] = u;
        atomicAdd(&h[u >> 21], 1u);
        __syncthreads();
        for (int j = tid; j < 2048; j += 256) {
            unsigned c = h[j];
            if (c) atomicAdd(&g_hist[j], c);
        }
        return;
    }

    // ---- loss tile role ----
    const int bf = bid - ZB;
    const int bx = bf % GX;
    const int brem = bf / GX;
    const int by = brem % GY;
    const int bz = brem / GY;
    const int x0 = bx * TX, y0 = by * TY, z0t = bz * TZ;

    // Stage d-tile (reflect halo) into LDS; div/mod hoisted out of zz loop.
    int goff[3], lp[3];
#pragma unroll
    for (int k = 0; k < 3; ++k) {
        int p = tid + 256 * k;
        lp[k] = (p < LSL) ? p : -1;
        if (p < LSL) {
            int xx = p % LX, yy = p / LX;
            int gy = refl(y0 + yy - 1, NY);
            int gx = refl(x0 + xx - 1, NX);
            goff[k] = gy * NXP + gx;
        }
    }
    for (int zz = 0; zz < LZ; ++zz) {
        int gz = refl(z0t + zz - 1, NZ);
        const float* __restrict__ pl = P + (size_t)gz * (NY * NXP);
#pragma unroll
        for (int k = 0; k < 3; ++k) {
            if (lp[k] >= 0) {
                float a = pl[goff[k]];
                float b = pl[goff[k] + 1];
                dt[zz * LSL + lp[k]] = b - a;
            }
        }
    }
    __syncthreads();

    const int x = tid & 31;
    const int y = tid >> 5;             // 0..7; chains at y and y+8
    const int lbA = y * LX + x;
    const int lbB = lbA + 8 * LX;

    auto rd9 = [&](int base, float* v) {
#pragma unroll
        for (int dy = 0; dy < 3; ++dy)
#pragma unroll
            for (int dxx = 0; dxx < 3; ++dxx)
                v[dy * 3 + dxx] = dt[base + dy * LX + dxx];
    };

    float SA0[9], SA1[9], SA2[9], SB0[9], SB1[9], SB2[9];
    float cA, cB, s_acc = 0.0f, m_acc = 0.0f;

    {
        float a9[9], b9[9];
        rd9(lbA, a9);            rd9(lbB, b9);
        OES<9>::run(a9, SA0);    OES<9>::run(b9, SB0);
        rd9(lbA + LSL, a9);      rd9(lbB + LSL, b9);
        cA = a9[4];              cB = b9[4];
        OES<9>::run(a9, SA1);    OES<9>::run(b9, SB1);
    }

    // One pair = 2 z-steps; roles rotate (X=oldest, Y=mid, Z=new-even slot).
    auto pairstep = [&](float (&XA)[9], float (&YA)[9], float (&ZA)[9],
                        float (&XB)[9], float (&YB)[9], float (&ZB_)[9], int t) {
        float a9[9], b9[9], MA[18], MB[18];
        // even step t: window (t, t+1, t+2)
        rd9(lbA + (t + 2) * LSL, a9);
        rd9(lbB + (t + 2) * LSL, b9);
        float cnA = a9[4], cnB = b9[4];
        OES<9>::run(a9, ZA);            OES<9>::run(b9, ZB_);
        OEM<9, 9>::run(YA, ZA, MA);     OEM<9, 9>::run(YB, ZB_, MB);
        float medA = sel27(XA, MA), medB = sel27(XB, MB);
        float dA = cA - medA, dB = cB - medB;
        s_acc = fmaf(dA, dA, fmaf(dB, dB, s_acc));
        m_acc = fmaxf(m_acc, fmaxf(1.0f - cA, 1.0f - cB));
        cA = cnA; cB = cnB;
        // odd step t+1: window (t+1, t+2, t+3); M reused, new slice -> X
        rd9(lbA + (t + 3) * LSL, a9);
        rd9(lbB + (t + 3) * LSL, b9);
        cnA = a9[4]; cnB = b9[4];
        OES<9>::run(a9, XA);            OES<9>::run(b9, XB);
        medA = sel27(XA, MA);           medB = sel27(XB, MB);
        dA = cA - medA; dB = cB - medB;
        s_acc = fmaf(dA, dA, fmaf(dB, dB, s_acc));
        m_acc = fmaxf(m_acc, fmaxf(1.0f - cA, 1.0f - cB));
        cA = cnA; cB = cnB;
    };

    // Rotation: after a pair, oldest=Z, mid=X, spare=Y  =>  (X,Y,Z)->(Z,X,Y)
    pairstep(SA0, SA1, SA2, SB0, SB1, SB2, 0);
    pairstep(SA2, SA0, SA1, SB2, SB0, SB1, 2);
    pairstep(SA1, SA2, SA0, SB1, SB2, SB0, 4);
    pairstep(SA0, SA1, SA2, SB0, SB1, SB2, 6);

    // Block reduction -> per-block partial (plain stores, no atomics).
#pragma unroll
    for (int off = 32; off > 0; off >>= 1) {
        s_acc += __shfl_down(s_acc, off);
        m_acc = fmaxf(m_acc, __shfl_down(m_acc, off));
    }
    __shared__ float ss[4], sm[4];
    const int lane = tid & 63, wid = tid >> 6;
    if (lane == 0) { ss[wid] = s_acc; sm[wid] = m_acc; }
    __syncthreads();
    if (tid == 0) {
        float S = (ss[0] + ss[1]) + (ss[2] + ss[3]);
        float M = fmaxf(fmaxf(sm[0], sm[1]), fmaxf(sm[2], sm[3]));
        g_ps[bf] = (double)S;
        g_pm[bf] = M;
    }
}

// Bucket-pick from g_hist + candidate counting-select + partial reduction.
// Re-zeroes g_hist at the end for the next call (graph-safe lifecycle).
__global__ __launch_bounds__(1024) void final_k(float* __restrict__ out) {
    __shared__ unsigned cand[2048];      // candidates, or radix hist (fallback)
    __shared__ unsigned s_cnt, s_med, s_b, s_r;
    __shared__ unsigned wsum[16], woff[16];
    const int tid = threadIdx.x;
    const int lane = tid & 63, wid = tid >> 6;
    const unsigned kk = (NZ0 - 1) / 2;   // 12287

    // ---- 1. pick the top-11-bit bucket containing rank kk ----
    unsigned h0 = g_hist[2 * tid], h1 = g_hist[2 * tid + 1];
    {
        unsigned mysum = h0 + h1, inc = mysum;
#pragma unroll
        for (int d = 1; d < 64; d <<= 1) { unsigned t2 = __shfl_up(inc, d); if (lane >= d) inc += t2; }
        if (lane == 63) wsum[wid] = inc;
        __syncthreads();
        if (tid == 0) { unsigned a = 0; for (int w = 0; w < 16; ++w) { woff[w] = a; a += wsum[w]; } }
        __syncthreads();
        unsigned exc = woff[wid] + inc - mysum;
        if (exc <= kk && kk < exc + h0) { s_b = 2u * tid; s_r = kk - exc; }
        exc += h0;
        if (exc <= kk && kk < exc + h1) { s_b = 2u * tid + 1u; s_r = kk - exc; }
    }
    __syncthreads();
    const unsigned b1 = s_b, k1 = s_r;
    // re-zero g_hist for the next call (values already consumed into regs)
    g_hist[2 * tid] = 0u; g_hist[2 * tid + 1] = 0u;

    // ---- 2. gather in-bucket candidates, exact counting-select ----
    if (tid == 0) s_cnt = 0u;
    __syncthreads();
    for (int i = tid; i < NZ0; i += 1024) {
        unsigned u = g_u[i];
        if ((u >> 21) == b1) {
            unsigned idx = atomicAdd(&s_cnt, 1u);
            if (idx < 2048u) cand[idx] = u;
        }
    }
    __syncthreads();
    const unsigned m = s_cnt;

    if (m <= 2048u) {
        for (int i = tid; i < (int)m; i += 1024) {
            unsigned c = cand[i], less = 0u, eq = 0u;
            for (unsigned j = 0; j < m; ++j) {
                unsigned v = cand[j];
                less += (v < c); eq += (v == c);
            }
            if (less <= k1 && k1 < less + eq) s_med = c;
        }
        __syncthreads();
    } else {
        // fallback: 11-bit + 10-bit radix passes over g_u (filtered)
        unsigned pref = b1, kx = k1;
        for (int j = tid; j < 2048; j += 1024) cand[j] = 0u;
        __syncthreads();
        for (int i = tid; i < NZ0; i += 1024) {
            unsigned u = g_u[i];
            if ((u >> 21) == pref) atomicAdd(&cand[(u >> 10) & 2047u], 1u);
        }
        __syncthreads();
        {
            unsigned c0 = cand[tid * 2], c1 = cand[tid * 2 + 1];
            unsigned mysum = c0 + c1, inc = mysum;
#pragma unroll
            for (int d = 1; d < 64; d <<= 1) { unsigned t2 = __shfl_up(inc, d); if (lane >= d) inc += t2; }
            if (lane == 63) wsum[wid] = inc;
            __syncthreads();
            if (tid == 0) { unsigned a = 0; for (int w = 0; w < 16; ++w) { woff[w] = a; a += wsum[w]; } }
            __syncthreads();
            unsigned exc = woff[wid] + inc - mysum;
            if (exc <= kx && kx < exc + c0) { s_b = tid * 2u; s_r = kx - exc; }
            exc += c0;
            if (exc <= kx && kx < exc + c1) { s_b = tid * 2u + 1u; s_r = kx - exc; }
        }
        __syncthreads();
        pref = (pref << 11) | s_b; kx = s_r;
        __syncthreads();
        for (int j = tid; j < 1024; j += 1024) cand[j] = 0u;
        __syncthreads();
        for (int i = tid; i < NZ0; i += 1024) {
            unsigned u = g_u[i];
            if ((u >> 10) == pref) atomicAdd(&cand[u & 1023u], 1u);
        }
        __syncthreads();
        {
            unsigned c0 = cand[tid], mysum = c0, inc = mysum;
#pragma unroll
            for (int d = 1; d < 64; d <<= 1) { unsigned t2 = __shfl_up(inc, d); if (lane >= d) inc += t2; }
            if (lane == 63) wsum[wid] = inc;
            __syncthreads();
            if (tid == 0) { unsigned a = 0; for (int w = 0; w < 16; ++w) { woff[w] = a; a += wsum[w]; } }
            __syncthreads();
            unsigned exc = woff[wid] + inc - mysum;
            if (exc <= kx && kx < exc + c0) s_b = (unsigned)tid;
        }
        __syncthreads();
        if (tid == 0) s_med = (pref << 10) | s_b;
        __syncthreads();
    }

    // ---- 3. reduce the 1152 per-block partials (fixed tree) ----
    double s = 0.0; float mm = 0.0f;
    if (tid < NBLK) { s = g_ps[tid]; mm = g_pm[tid]; }
    if (tid < NBLK - 1024) { s += g_ps[1024 + tid]; mm = fmaxf(mm, g_pm[1024 + tid]); }
#pragma unroll
    for (int off = 32; off > 0; off >>= 1) {
        s += __shfl_down(s, off);
        mm = fmaxf(mm, __shfl_down(mm, off));
    }
    __shared__ double sd[16];
    __shared__ float sf[16];
    if (lane == 0) { sd[wid] = s; sf[wid] = mm; }
    __syncthreads();
    if (tid == 0) {
        double S = 0.0; float M = 0.0f;
        for (int w = 0; w < 16; ++w) { S += sd[w]; M = fmaxf(M, sf[w]); }
        unsigned u = s_med;
        unsigned bits = (u & 0x80000000u) ? (u ^ 0x80000000u) : ~u;
        float med = __uint_as_float(bits);
        out[0] = (float)(S / (double)NVOX);
        out[1] = M;
        out[2] = med * med;
    }
}

extern "C" void kernel_launch(void* const* d_in, const int* in_sizes, int n_in,
                              void* d_out, int out_size, void* d_ws, size_t ws_size,
                              hipStream_t stream) {
    const float* P = (const float*)d_in[0];
    float* out = (float*)d_out;

    hipLaunchKernelGGL(fused_main, dim3(ZB + NBLK), dim3(256), 0, stream, P);
    hipLaunchKernelGGL(final_k, dim3(1), dim3(1024), 0, stream, out);
}